// Round 1
// baseline (1904.422 us; speedup 1.0000x reference)
//
#include <hip/hip_runtime.h>
#include <stdint.h>

typedef unsigned short u16;
typedef __attribute__((ext_vector_type(8))) short bfrag8;   // 8 bf16 (4 VGPRs)
typedef __attribute__((ext_vector_type(4))) float f32x4;

#define DEV static __device__ __forceinline__

DEV u16 f2bf(float f) {                    // RNE f32 -> bf16 (finite inputs)
  uint32_t u = __float_as_uint(f);
  u += 0x7fffu + ((u >> 16) & 1u);
  return (u16)(u >> 16);
}

// async global->LDS, 16B per lane. LDS dest is wave-uniform base; HW adds lane*16.
DEV void async_lds16(const void* g, void* l) {
  const __attribute__((address_space(1))) uint32_t* gp =
      (const __attribute__((address_space(1))) uint32_t*)(uintptr_t)g;
  __attribute__((address_space(3))) uint32_t* lp =
      (__attribute__((address_space(3))) uint32_t*)(uint32_t)(uintptr_t)l;  // low 32 bits = LDS offset
  __builtin_amdgcn_global_load_lds(gp, lp, 16, 0, 0);
}

// shift table {-4,1,2,-1,0,3,-2,-3,4} packed as nibbles (+4), idx=(i%3)*3+(j%3)
DEV int shift_of(int n) {
  int i = n / 7, j = n - i * 7;
  int idx = (i % 3) * 3 + (j % 3);
  return (int)((0x812743650ull >> (4 * idx)) & 15ull) - 4;
}

// ---------------- f32 -> bf16 cast ----------------
__global__ void k_f32_to_bf16(const float* __restrict__ src, u16* __restrict__ dst, int n4) {
  int i = blockIdx.x * blockDim.x + threadIdx.x;
  const int stride = gridDim.x * blockDim.x;
  for (; i < n4; i += stride) {
    float4 v = ((const float4*)src)[i];
    union { u16 h[4]; uint2 u; } o;
    o.h[0] = f2bf(v.x); o.h[1] = f2bf(v.y); o.h[2] = f2bf(v.z); o.h[3] = f2bf(v.w);
    ((uint2*)dst)[i] = o.u;
  }
}

// ---------------- bias pre-gather: bias[h][n][m] ----------------
__global__ void k_bias_pre(const float* __restrict__ tab, const int* __restrict__ ridx,
                           float* __restrict__ bp) {
  int nm = blockIdx.x * blockDim.x + threadIdx.x;
  if (nm < 2401) {
    int idx = ridx[nm];
#pragma unroll
    for (int h = 0; h < 16; ++h) bp[h * 2401 + nm] = tab[idx * 16 + h];
  }
}

// ---------------- NT bf16 GEMM: C[M,N] = A[M,K] * B[N,K]^T (+bias) ----------------
// m97 structure: 128x128 tile, BK=32, 4 waves of 64x64, global_load_lds width 16.
template <int OUT_F32>
__global__ __launch_bounds__(256) void k_gemm_bt(const u16* __restrict__ A,
                                                 const u16* __restrict__ B,
                                                 void* __restrict__ Cp,
                                                 const float* __restrict__ bias,
                                                 int M, int N, int K) {
  __shared__ __align__(16) u16 As[4096];  // [128][32]
  __shared__ __align__(16) u16 Bs[4096];  // [128][32]
  const int tid = threadIdx.x;
  const int wave = tid >> 6, lane = tid & 63;
  const int quad = lane >> 4, l16 = lane & 15;
  const int wm = ((wave >> 1) & 1) << 6;
  const int wn = (wave & 1) << 6;
  const int bm = blockIdx.x, bn = blockIdx.y;

  f32x4 acc[4][4] = {};

  const int srow = lane >> 2;          // row within 16-row region
  const int scol = (lane & 3) << 3;    // 8-elem (16B) chunk within 64B row
  const u16* ga = A + (long)(bm * 128 + srow) * K + scol;
  const u16* gb = B + (long)(bn * 128 + srow) * K + scol;
  const long rstep = (long)16 * K;

  for (int k0 = 0; k0 < K; k0 += 32) {
#pragma unroll
    for (int tt = 0; tt < 2; ++tt) {
      const int region = wave * 2 + tt;          // 8 regions of 16 rows
      async_lds16(ga + region * rstep + k0, &As[region * 512]);
      async_lds16(gb + region * rstep + k0, &Bs[region * 512]);
    }
    __syncthreads();   // drains vmcnt -> LDS filled
    bfrag8 af[4], bq[4];
#pragma unroll
    for (int mt = 0; mt < 4; ++mt)
      af[mt] = *(const bfrag8*)&As[(wm + mt * 16 + l16) * 32 + quad * 8];
#pragma unroll
    for (int nt = 0; nt < 4; ++nt)
      bq[nt] = *(const bfrag8*)&Bs[(wn + nt * 16 + l16) * 32 + quad * 8];
#pragma unroll
    for (int mt = 0; mt < 4; ++mt)
#pragma unroll
      for (int nt = 0; nt < 4; ++nt)
        acc[mt][nt] = __builtin_amdgcn_mfma_f32_16x16x32_bf16(af[mt], bq[nt], acc[mt][nt], 0, 0, 0);
    __syncthreads();
  }

#pragma unroll
  for (int nt = 0; nt < 4; ++nt) {
    const int col = (bn << 7) + wn + nt * 16 + l16;
    float bv = 0.f;
    if (OUT_F32) bv = bias[col];
#pragma unroll
    for (int mt = 0; mt < 4; ++mt)
#pragma unroll
      for (int i = 0; i < 4; ++i) {
        const long row = (long)(bm << 7) + wm + mt * 16 + quad * 4 + i;
        const float v = acc[mt][nt][i] + bv;
        if (OUT_F32) ((float*)Cp)[row * N + col] = v;
        else         ((u16*)Cp)[row * N + col] = f2bf(v);
      }
  }
}

// ---------------- fused shifted window attention ----------------
// One wave per (bflat, h) unit; 4 units per block. qkv: [M,1536] bf16 (q|k|v per head).
// out_pre: [M,512] bf16, inverse shift folded into store.
__global__ __launch_bounds__(256) void k_attn(const u16* __restrict__ qkv,
                                              const float* __restrict__ bias_pre,
                                              u16* __restrict__ out_pre) {
  __shared__ __align__(16) u16 smem[4][6144];  // per wave: qs[64][32] ks[64][32] vt[32][64]; ps aliases qs+ks
  const int tid = threadIdx.x;
  const int wave = tid >> 6, lane = tid & 63;
  const int quad = lane >> 4, l16 = lane & 15;

  const int unit = (blockIdx.x << 2) + wave;  // 0..65535
  const int h = unit & 15;
  const int bflat = unit >> 4;
  const int w = bflat & 63;
  const int t = (bflat >> 6) & 15;
  const int b = bflat >> 10;

  u16* qs = &smem[wave][0];
  u16* ks = &smem[wave][2048];
  u16* vt = &smem[wave][4096];
  u16* ps = &smem[wave][0];     // [64][64] over dead q/k after QK^T

  // zero vt pad (cols 48..63; col 48 rewritten by staging) — NaN safety for PV
#pragma unroll
  for (int it = 0; it < 8; ++it) {
    int idx = it * 64 + lane;
    vt[(idx >> 4) * 64 + 48 + (idx & 15)] = 0;
  }

  const int r_off = lane >> 2;
  const int ch8 = (lane & 3) << 3;

  // q,k: shifted gather straight into LDS (64 rows; rows>=49 clamp to 48 -> finite garbage)
#pragma unroll
  for (int pass = 0; pass < 4; ++pass) {
    int r = pass * 16 + r_off;
    int rc = r > 48 ? 48 : r;
    int ts = (t - shift_of(rc) + 16) & 15;
    long row = ((long)((b * 16 + ts) * 64 + w)) * 49 + rc;
    const u16* gq = qkv + row * 1536 + h * 32 + ch8;
    async_lds16(gq, qs + pass * 512);
    async_lds16(gq + 512, ks + pass * 512);
  }
  // v: shifted gather + transpose into vt[cc][m]
#pragma unroll
  for (int pass = 0; pass < 4; ++pass) {
    int r = pass * 16 + r_off;
    if (r < 49) {
      int ts = (t - shift_of(r) + 16) & 15;
      long row = ((long)((b * 16 + ts) * 64 + w)) * 49 + r;
      uint4 d = *(const uint4*)(qkv + row * 1536 + 1024 + h * 32 + ch8);
      const u16* pd = (const u16*)&d;
#pragma unroll
      for (int jj = 0; jj < 8; ++jj) vt[(ch8 + jj) * 64 + r] = pd[jj];
    }
  }

  __builtin_amdgcn_s_waitcnt(0);       // drain LDS-DMA + ds writes (wave-private unit, no barrier)
  __builtin_amdgcn_sched_barrier(0);

  // S = Q K^T  (A/B frags: rows x 32k contiguous; C/D: col=l16, row=quad*4+i)
  bfrag8 aq[4], bk[4];
#pragma unroll
  for (int tn = 0; tn < 4; ++tn) aq[tn] = *(const bfrag8*)&qs[(tn * 16 + l16) * 32 + quad * 8];
#pragma unroll
  for (int tm = 0; tm < 4; ++tm) bk[tm] = *(const bfrag8*)&ks[(tm * 16 + l16) * 32 + quad * 8];

  f32x4 s[4][4] = {};
#pragma unroll
  for (int tn = 0; tn < 4; ++tn)
#pragma unroll
    for (int tm = 0; tm < 4; ++tm)
      s[tn][tm] = __builtin_amdgcn_mfma_f32_16x16x32_bf16(aq[tn], bk[tm], s[tn][tm], 0, 0, 0);

  const float scale = 0.17677669529663687f;  // 32^-0.5
#pragma unroll
  for (int tm = 0; tm < 4; ++tm) {
    const int col = tm * 16 + l16;
    const bool valid = col < 49;
    const float* bp = bias_pre + h * 2401 + col;
#pragma unroll
    for (int tn = 0; tn < 4; ++tn)
#pragma unroll
      for (int i = 0; i < 4; ++i) {
        const int row = tn * 16 + quad * 4 + i;
        const int rowc = row > 48 ? 48 : row;
        s[tn][tm][i] = valid ? (s[tn][tm][i] * scale + bp[rowc * 49]) : -1e30f;
      }
  }

  // online row max / exp / sum; P (unnormalized) -> bf16 into ps; 1/l applied at store
  float rinv[4][4];
#pragma unroll
  for (int tn = 0; tn < 4; ++tn) {
#pragma unroll
    for (int i = 0; i < 4; ++i) {
      float m = fmaxf(fmaxf(s[tn][0][i], s[tn][1][i]), fmaxf(s[tn][2][i], s[tn][3][i]));
      m = fmaxf(m, __shfl_xor(m, 1));
      m = fmaxf(m, __shfl_xor(m, 2));
      m = fmaxf(m, __shfl_xor(m, 4));
      m = fmaxf(m, __shfl_xor(m, 8));
      float l = 0.f;
#pragma unroll
      for (int tm = 0; tm < 4; ++tm) {
        float p = __expf(s[tn][tm][i] - m);
        l += p;
        ps[(tn * 16 + quad * 4 + i) * 64 + tm * 16 + l16] = f2bf(p);
      }
      l += __shfl_xor(l, 1);
      l += __shfl_xor(l, 2);
      l += __shfl_xor(l, 4);
      l += __shfl_xor(l, 8);
      rinv[tn][i] = 1.0f / l;
    }
  }

  // O = P V   (A from ps rows; B from vt[cc][m] rows)
  f32x4 o[4][2] = {};
#pragma unroll
  for (int kt = 0; kt < 2; ++kt) {
    bfrag8 ap[4], bv[2];
#pragma unroll
    for (int tn = 0; tn < 4; ++tn)
      ap[tn] = *(const bfrag8*)&ps[(tn * 16 + l16) * 64 + kt * 32 + quad * 8];
#pragma unroll
    for (int ct = 0; ct < 2; ++ct)
      bv[ct] = *(const bfrag8*)&vt[(ct * 16 + l16) * 64 + kt * 32 + quad * 8];
#pragma unroll
    for (int tn = 0; tn < 4; ++tn)
#pragma unroll
      for (int ct = 0; ct < 2; ++ct)
        o[tn][ct] = __builtin_amdgcn_mfma_f32_16x16x32_bf16(ap[tn], bv[ct], o[tn][ct], 0, 0, 0);
  }

  // store with inverse shift (same time map as q gather)
#pragma unroll
  for (int tn = 0; tn < 4; ++tn)
#pragma unroll
    for (int i = 0; i < 4; ++i) {
      const int row = tn * 16 + quad * 4 + i;
      if (row < 49) {
        const int ts = (t - shift_of(row) + 16) & 15;
        const long fd = (long)((b * 16 + ts) * 64 + w);
        const long base = (fd * 49 + row) * 512 + h * 32;
        const float r = rinv[tn][i];
        out_pre[base + l16]      = f2bf(o[tn][0][i] * r);
        out_pre[base + 16 + l16] = f2bf(o[tn][1][i] * r);
      }
    }
}

// ---------------- launch ----------------
extern "C" void kernel_launch(void* const* d_in, const int* in_sizes, int n_in,
                              void* d_out, int out_size, void* d_ws, size_t ws_size,
                              hipStream_t stream) {
  const float* x       = (const float*)d_in[0];
  const float* qkv_w   = (const float*)d_in[1];
  const float* proj_w  = (const float*)d_in[2];
  const float* proj_b  = (const float*)d_in[3];
  const float* rel_tab = (const float*)d_in[4];
  const int*   rel_idx = (const int*)d_in[5];
  // d_in[6]=batch_size(4), d_in[7]=frame_len(16): fixed by setup, hardcoded.

  const long M = 200704;  // 4096*49
  char* ws = (char*)d_ws;
  u16*   x_bf     = (u16*)ws;                                    // M*512 bf16 (reused as attn_out)
  u16*   qkvw_bf  = (u16*)(ws + 205520896);                      // 1536*512
  u16*   projw_bf = (u16*)(ws + 205520896 + 1572864);            // 512*512
  float* bias_pre = (float*)(ws + 205520896 + 1572864 + 524288); // 16*2401 (+slack)
  u16*   qkv_buf  = (u16*)(ws + 205520896 + 1572864 + 524288 + 262144); // M*1536 bf16

  k_f32_to_bf16<<<4096, 256, 0, stream>>>(x, x_bf, (int)(M * 512 / 4));
  k_f32_to_bf16<<<768, 256, 0, stream>>>(qkv_w, qkvw_bf, 1536 * 512 / 4);
  k_f32_to_bf16<<<256, 256, 0, stream>>>(proj_w, projw_bf, 512 * 512 / 4);
  k_bias_pre<<<10, 256, 0, stream>>>(rel_tab, rel_idx, bias_pre);

  dim3 g1(1568, 12);
  k_gemm_bt<0><<<g1, 256, 0, stream>>>(x_bf, qkvw_bf, (void*)qkv_buf, nullptr, (int)M, 1536, 512);

  u16* attn_out = x_bf;  // x_bf dead after gemm1
  k_attn<<<16384, 256, 0, stream>>>(qkv_buf, bias_pre, attn_out);

  dim3 g2(1568, 4);
  k_gemm_bt<1><<<g2, 256, 0, stream>>>(attn_out, projw_bf, d_out, proj_b, (int)M, 512, 512);
}